// Round 9
// baseline (205.908 us; speedup 1.0000x reference)
//
#include <hip/hip_runtime.h>

// y[e] = W2 . relu(W1 . concat(z[src[e]], z[dst[e]]) + b1) + b2
// N=50000, D=128, H=512, E=500000. 131 GFLOP in GEMM1.
// R16: split the barrier domain. Corrected cycle model (R15 post-mortem:
// MFMA cyc constants are per-CU; per-SIMD a 32x32x16 is ~32cyc): per tile
// matrix = 4096 cyc/SIMD, LDS = ~4.4K cyc/CU, measured 9.57K == the SUM ->
// pipes serialize because all 8 waves share one per-tile barrier (stalls
// phase-correlated). Fix: 2 independent blocks/CU - grid 512 = (tile, hy),
// 256-thr blocks of 4 waves x 64h; hy picks the 256-h half of H=512.
// Two co-resident blocks run different tiles on different barriers ->
// cross-block overlap (m114) fills stalls. Cost: each tile gathered twice
// (FETCH ~2x, still ~20% of HBM peak; LDS-write conflicts ~2x).
// Everything else verbatim R15: persistent blocks, W1-in-regs (128/wave),
// 32x32x16 MFMA operand-swapped (C row=h col=edge), mid-tile gather issue
// via global_load_lds, source-side XOR swizzle, b1 in acc init, atomic
// epilogue into b2-prefilled out, single barrier + vmcnt ledger
// ([8 gathers][8 idx][2 atomics] -> vmcnt(10)).

typedef __bf16 bf16x8 __attribute__((ext_vector_type(8)));
typedef float f32x4  __attribute__((ext_vector_type(4)));
typedef float f32x16 __attribute__((ext_vector_type(16)));

__device__ __forceinline__ unsigned short f2b(float f) {
    unsigned int u = __float_as_uint(f);
    u = (u + 0x7fffu + ((u >> 16) & 1u)) >> 16;   // RNE
    return (unsigned short)u;
}

__device__ __forceinline__ void gload_lds16(const unsigned short* g, unsigned short* l) {
    __builtin_amdgcn_global_load_lds(
        (const __attribute__((address_space(1))) unsigned int*)g,
        (__attribute__((address_space(3))) unsigned int*)l, 16, 0, 0);
}

// zb: z as bf16 [N][128].  w1s: W1 in 32x32x16 A-fragment order:
// w1s[(hb*16 + kst)*512 + lane*8 + t]
//   = bf16(W1[hb*32 + (lane&31)][kst*16 + (lane>>5)*8 + t]),  hb,kst in 0..15
// Also pre-fills out[] with b2 (atomicAdd target).
__global__ void prep_kernel(const float* __restrict__ z, const float* __restrict__ W1,
                            const float* __restrict__ b2p,
                            unsigned short* __restrict__ zb, unsigned short* __restrict__ w1s,
                            float* __restrict__ outz, int nz4, int nout4) {
    int stride = gridDim.x * blockDim.x;
    const int nw = 256 * 64;   // (hb*16+kst) x lane
    const int total = nz4 + nw + nout4;
    const float b2v = b2p[0];
    for (int idx = blockIdx.x * blockDim.x + threadIdx.x; idx < total; idx += stride) {
        if (idx < nz4) {
            float4 v = ((const float4*)z)[idx];
            ushort4 o;
            o.x = f2b(v.x); o.y = f2b(v.y); o.z = f2b(v.z); o.w = f2b(v.w);
            ((ushort4*)zb)[idx] = o;
        } else if (idx < nz4 + nw) {
            int u = idx - nz4;            // 0..16383
            int lane = u & 63;
            int blk  = u >> 6;            // hb*16 + kst
            int h  = (blk >> 4) * 32 + (lane & 31);
            int kb = (blk & 15) * 16 + (lane >> 5) * 8;
            const float* src = W1 + h * 256 + kb;
            ushort4 o0, o1;
            float4 v0 = *(const float4*)(src);
            float4 v1 = *(const float4*)(src + 4);
            o0.x = f2b(v0.x); o0.y = f2b(v0.y); o0.z = f2b(v0.z); o0.w = f2b(v0.w);
            o1.x = f2b(v1.x); o1.y = f2b(v1.y); o1.z = f2b(v1.z); o1.w = f2b(v1.w);
            ushort4* dst = (ushort4*)(w1s + u * 8);
            dst[0] = o0; dst[1] = o1;
        } else {
            ((float4*)outz)[idx - nz4 - nw] = (float4){b2v, b2v, b2v, b2v};
        }
    }
}

__global__ __launch_bounds__(256, 2)
void edge_mlp_kernel(const int* __restrict__ ei, const unsigned short* __restrict__ zb,
                     const unsigned short* __restrict__ w1s,
                     const float* __restrict__ b1, const float* __restrict__ W2,
                     float* __restrict__ out, int E, int ntiles) {
    __shared__ unsigned short ldsA[2][64 * 256];  // 64 KB, dbuf A tiles
    __shared__ float ldsB1[256];                  // 1 KB staged b1 (this hy half)
    __shared__ float ldsW2[256];                  // 1 KB staged W2 (this hy half)

    const int tid  = threadIdx.x;
    const int lane = tid & 63;
    const int w    = tid >> 6;        // 0..3 : 64-h slice within this hy half
    const int l31  = lane & 31;
    const int hi   = lane >> 5;       // 0/1 : k-half within frag, C row-group
    const int hy   = blockIdx.x & 1;  // which 256-h half of H=512
    const int t0   = blockIdx.x >> 1; // 0..255 : starting tile
    const int Gt   = gridDim.x >> 1;  // tile stride (256)
    if (t0 >= ntiles) return;

    ldsB1[tid] = b1[hy * 256 + tid];
    ldsW2[tid] = W2[hy * 256 + tid];

    // ---- persistent W1: wave w holds hb hy*8+w*2, +1 (64 h), in regs ----
    uint4 breg[2][16];                // 128 regs
    #pragma unroll
    for (int j = 0; j < 2; ++j)
        #pragma unroll
        for (int kst = 0; kst < 16; ++kst)
            breg[j][kst] = *(const uint4*)(w1s + (((hy * 8 + w * 2 + j) * 16 + kst) << 9) + lane * 8);

    // gather: instr q covers rows m=(w*16+q*2)+hi; lane L writes LDS slot
    // L&31 of the row pair; source k-slot pre-swizzled: side*16 + (l15^(m&7)).
    const int side = (lane >> 4) & 1;
    const int l15  = lane & 15;
    const int swz3 = (l31 & 7) << 3;  // read-side XOR on the low-4 slot bits (x8 elems)

#define ISSUE_GATHER(BUF)                                                     \
    do {                                                                      \
        _Pragma("unroll")                                                     \
        for (int q_ = 0; q_ < 8; ++q_) {                                      \
            int m_   = w * 16 + q_ * 2 + hi;                                  \
            int s15_ = l15 ^ (m_ & 7);                                        \
            gload_lds16(zb + (((long)ival[q_]) << 7) + (s15_ << 3),           \
                        &ldsA[BUF][(w * 16 + q_ * 2) << 8]);                  \
        }                                                                     \
    } while (0)

    // drain staging loads (breg/b1/W2) so the vmcnt ledger starts clean
    asm volatile("s_waitcnt vmcnt(0) lgkmcnt(0)" ::: "memory");

    // ---- prologue: idx(T0) -> gather(T0) -> idx(T1) -> 2 zero-atomics ----
    int ival[8];
    #pragma unroll
    for (int q = 0; q < 8; ++q) {
        int e = t0 * 64 + w * 16 + q * 2 + hi;
        e = (e < E) ? e : (E - 1);
        ival[q] = ei[side * E + e];
    }
    ISSUE_GATHER(0);
    asm volatile("" ::: "memory");     // pin: idx(T1) stays AFTER gathers
    {
        int t1 = t0 + Gt;
        #pragma unroll
        for (int q = 0; q < 8; ++q) {
            int e = t1 * 64 + w * 16 + q * 2 + hi;
            e = (e < E) ? e : (E - 1);
            ival[q] = ei[side * E + e];
        }
    }
    asm volatile("" ::: "memory");     // pin: zero-atomics AFTER idx(T1)
    if (hi == 0) {                     // 2 queue-padding atomics (add 0.0f)
        atomicAdd(&out[t0 * 64 + l31], 0.0f);
        atomicAdd(&out[t0 * 64 + 32 + l31], 0.0f);
    }

    int cur = 0;
    for (int t = t0; t < ntiles; t += Gt) {
        // own 8 gathers are oldest; 8 idx + 2 atomics are newer -> vmcnt(10)
        asm volatile("s_waitcnt vmcnt(10)" ::: "memory");
        __builtin_amdgcn_s_barrier();
        asm volatile("" ::: "memory");

        const unsigned short* bufc = &ldsA[cur][0];

        // acc init = b1 (acc ends as W1.x + b1); C row=h, col=edge
        // local h(j,reg) = w*64 + j*32 + (reg&3) + 8*(reg>>2) + 4*hi
        f32x16 acc[2][2];                 // [edge-blk i][h-blk j]
        #pragma unroll
        for (int j = 0; j < 2; ++j)
            #pragma unroll
            for (int q = 0; q < 4; ++q) {
                f32x4 b = *(const f32x4*)&ldsB1[w * 64 + j * 32 + q * 8 + hi * 4];
                #pragma unroll
                for (int rr = 0; rr < 4; ++rr) {
                    acc[0][j][q * 4 + rr] = b[rr];
                    acc[1][j][q * 4 + rr] = b[rr];
                }
            }

        __builtin_amdgcn_s_setprio(1);
        #pragma unroll
        for (int kst = 0; kst < 8; ++kst) {
            bf16x8 a[2];
            #pragma unroll
            for (int i = 0; i < 2; ++i) {
                int s = kst * 2 + hi;     // logical 16B k-slot 0..31
                int off = ((i * 32 + l31) << 8) + ((s & 16) << 3) + (((s & 15) << 3) ^ swz3);
                a[i] = *(const bf16x8*)&bufc[off];
            }
            #pragma unroll
            for (int i = 0; i < 2; ++i)
                #pragma unroll
                for (int j = 0; j < 2; ++j)
                    acc[i][j] = __builtin_amdgcn_mfma_f32_32x32x16_bf16(
                        *(const bf16x8*)&breg[j][kst], a[i], acc[i][j], 0, 0, 0);
        }
        __builtin_amdgcn_s_setprio(0);

        // issue next tile's gathers (HBM latency hides under kst 8..15)
        ISSUE_GATHER(cur ^ 1);
        asm volatile("" ::: "memory");

        __builtin_amdgcn_s_setprio(1);
        #pragma unroll
        for (int kst = 8; kst < 16; ++kst) {
            bf16x8 a[2];
            #pragma unroll
            for (int i = 0; i < 2; ++i) {
                int s = kst * 2 + hi;
                int off = ((i * 32 + l31) << 8) + ((s & 16) << 3) + (((s & 15) << 3) ^ swz3);
                a[i] = *(const bf16x8*)&bufc[off];
            }
            #pragma unroll
            for (int i = 0; i < 2; ++i)
                #pragma unroll
                for (int j = 0; j < 2; ++j)
                    acc[i][j] = __builtin_amdgcn_mfma_f32_32x32x16_bf16(
                        *(const bf16x8*)&breg[j][kst], a[i], acc[i][j], 0, 0, 0);
        }
        __builtin_amdgcn_s_setprio(0);

        // tail: idx for tile t+2Gt (consumed by NEXT iter's gather-issue)
        {
            int tt = t + 2 * Gt;
            #pragma unroll
            for (int q = 0; q < 8; ++q) {
                int e = tt * 64 + w * 16 + q * 2 + hi;
                e = (e < E) ? e : (E - 1);
                ival[q] = ei[side * E + e];
            }
        }
        asm volatile("" ::: "memory");  // pin: epilogue atomics AFTER idx

        // epilogue: y-partial = sum_{h in slice} relu(acc)*w2 ;
        // in-reg over (j,reg) + 1 shuffle (xor32); 2 atomics (hi==0 lanes)
        float s2[2];
        #pragma unroll
        for (int i = 0; i < 2; ++i) {
            float s = 0.f;
            #pragma unroll
            for (int j = 0; j < 2; ++j)
                #pragma unroll
                for (int q = 0; q < 4; ++q) {
                    f32x4 w2q = *(const f32x4*)&ldsW2[w * 64 + j * 32 + q * 8 + hi * 4];
                    #pragma unroll
                    for (int rr = 0; rr < 4; ++rr)
                        s = fmaf(fmaxf(acc[i][j][q * 4 + rr], 0.f), w2q[rr], s);
                }
            s += __shfl_xor(s, 32);
            s2[i] = s;
        }
        #pragma unroll
        for (int i = 0; i < 2; ++i) {
            int e = t * 64 + i * 32 + l31;
            if (hi == 0 && e < E) atomicAdd(&out[e], s2[i]);
        }

        cur ^= 1;
    }
#undef ISSUE_GATHER
}

extern "C" void kernel_launch(void* const* d_in, const int* in_sizes, int n_in,
                              void* d_out, int out_size, void* d_ws, size_t ws_size,
                              hipStream_t stream) {
    const float* z  = (const float*)d_in[0];
    const int*   ei = (const int*)d_in[1];
    const float* W1 = (const float*)d_in[2];
    const float* b1 = (const float*)d_in[3];
    const float* W2 = (const float*)d_in[4];
    const float* b2 = (const float*)d_in[5];
    float* out = (float*)d_out;

    const int E  = in_sizes[1] / 2;   // 500000
    const int NZ = in_sizes[0];       // 6400000 = N*D

    unsigned short* zb  = (unsigned short*)d_ws;       // 12.8 MB
    unsigned short* w1s = zb + NZ;                     // 256 KB (swizzled W1)

    prep_kernel<<<2048, 256, 0, stream>>>(z, W1, b2, zb, w1s, out, NZ / 4, E / 4);

    const int ntiles = (E + 63) / 64;                  // 7813
    // grid 512 = (tile t0 = bid>>1, hy = bid&1); 2 blocks/CU, independent
    // barrier domains per CU; consecutive bids share a tile (L2 locality).
    edge_mlp_kernel<<<512, 256, 0, stream>>>(ei, zb, w1s, b1, W2, out, E, ntiles);
}